// Round 4
// baseline (112.747 us; speedup 1.0000x reference)
//
#include <hip/hip_runtime.h>

namespace {
constexpr int Bn = 8, Cn = 256, Hn = 96, Wn = 128;
constexpr int HWn = Hn * Wn;            // 12288
constexpr int CHWn = Cn * HWn;
constexpr int ND = 9;                   // 2*MD+1
constexpr int TILESH = Hn / 4;          // 24 tiles of 4 h-rows
constexpr int NBLK = Bn * TILESH * ND;  // 1728 blocks x 2 waves = 3456 waves
constexpr int PERX = NBLK / 8;          // 216 blocks/XCD -> one batch image per XCD
constexpr int NW = 2;                   // waves per block (channel split)
constexpr int CPW = Cn / NW;            // 128 channels per wave
}

// DPP lane shifts within 16-lane rows; bound_ctrl=true -> shifted-in lanes read 0
// (this IS the w-direction zero padding at tile edges).
__device__ __forceinline__ float dpp_shr1(float x) {  // lane i <- lane i-1 (row-local)
  return __int_as_float(__builtin_amdgcn_update_dpp(
      0, __float_as_int(x), 0x111 /*row_shr:1*/, 0xF, 0xF, true));
}
__device__ __forceinline__ float dpp_shl1(float x) {  // lane i <- lane i+1 (row-local)
  return __int_as_float(__builtin_amdgcn_update_dpp(
      0, __float_as_int(x), 0x101 /*row_shl:1*/, 0xF, 0xF, true));
}

struct Ch {
  float4 sa, sb, fa, fb;
};

__global__ __launch_bounds__(128) void corr_kernel(
    const float* __restrict__ first, const float* __restrict__ second,
    float* __restrict__ out)
{
  // cross-wave partial-sum exchange: red[dx][p][lane]
  __shared__ float red[ND][8][64];

  const int tid = threadIdx.x;
  const int wv = tid >> 6;    // 0..1: channel-slice owner
  const int lane = tid & 63;
  const int bid = blockIdx.x;
  // XCD-aware swizzle: XCD x handles batch image b=x -> second re-reads stay in its L2.
  const int logical = (bid & 7) * PERX + (bid >> 3);
  const int dy = logical % ND;
  const int t = logical / ND;
  const int b = t / TILESH;
  const int h0 = (t % TILESH) * 4;

  const int hs = lane >> 4;          // 0..3: h-row within tile (= DPP row group)
  const int w0 = (lane & 15) << 3;   // 0..120: 8 pixels per lane

  const int gr = h0 + hs + dy - 4;                    // second source row
  const float m = (gr >= 0 && gr < Hn) ? 1.0f : 0.0f; // row OOB mask (per 16-lane group)
  const int cg = min(max(gr, 0), Hn - 1);             // clamped (safe) row

  const float* ssrc = second + b * CHWn + wv * CPW * HWn + cg * Wn + w0;
  const float* fsrc = first + b * CHWn + wv * CPW * HWn + (h0 + hs) * Wn + w0;

  float acc[ND][8];
#pragma unroll
  for (int dx = 0; dx < ND; ++dx)
#pragma unroll
    for (int p = 0; p < 8; ++p) acc[dx][p] = 0.f;

  auto LOADCH = [&](int coff) -> Ch {
    Ch r;
    r.sa = *(const float4*)(ssrc + coff);
    r.sb = *(const float4*)(ssrc + coff + 4);
    r.fa = *(const float4*)(fsrc + coff);
    r.fb = *(const float4*)(fsrc + coff + 4);
    return r;
  };

  // NOTE: no per-channel row mask here — every s-value in a lane's window comes
  // from the same second-row (DPP is row-local), so acc scales linearly by m;
  // the mask is applied once in the epilogue. Saves 8 VALU/channel.
  auto COMP = [&](const Ch& ch) {
    const float s[16] = {
        dpp_shr1(ch.sb.x), dpp_shr1(ch.sb.y), dpp_shr1(ch.sb.z), dpp_shr1(ch.sb.w),
        ch.sa.x, ch.sa.y, ch.sa.z, ch.sa.w,
        ch.sb.x, ch.sb.y, ch.sb.z, ch.sb.w,
        dpp_shl1(ch.sa.x), dpp_shl1(ch.sa.y), dpp_shl1(ch.sa.z), dpp_shl1(ch.sa.w)};
    const float f[8] = {ch.fa.x, ch.fa.y, ch.fa.z, ch.fa.w,
                        ch.fb.x, ch.fb.y, ch.fb.z, ch.fb.w};
#pragma unroll
    for (int dx = 0; dx < ND; ++dx)
#pragma unroll
      for (int p = 0; p < 8; ++p)
        acc[dx][p] = fmaf(f[p], s[p + dx], acc[dx][p]);
  };

  // depth-2 register pipeline over this wave's 128 channels (R2's proven form)
  Ch L0 = LOADCH(0);
  Ch L1 = LOADCH(HWn);
  int coff = 2 * HWn;
#pragma unroll 1
  for (int it = 0; it < (CPW - 2) / 2; ++it) {  // 63 iters
    Ch N0 = LOADCH(coff);
    Ch N1 = LOADCH(coff + HWn);
    COMP(L0);
    COMP(L1);
    L0 = N0;
    L1 = N1;
    coff += 2 * HWn;
  }
  COMP(L0);
  COMP(L1);

  // ---- epilogue: cross-wave reduce, split store (wave0 -> dx 0..4, wave1 -> dx 5..8)
  const float scale = m * (1.0f / Cn);
  float* obase = out + ((b * 81 + dy * ND) * Hn + (h0 + hs)) * Wn + w0;

  if (wv == 0) {
#pragma unroll
    for (int dx = 5; dx < ND; ++dx)
#pragma unroll
      for (int p = 0; p < 8; ++p) red[dx][p][lane] = acc[dx][p];
  } else {
#pragma unroll
    for (int dx = 0; dx < 5; ++dx)
#pragma unroll
      for (int p = 0; p < 8; ++p) red[dx][p][lane] = acc[dx][p];
  }
  __syncthreads();

  const int dlo = (wv == 0) ? 0 : 5;
  const int dhi = (wv == 0) ? 5 : ND;
#pragma unroll
  for (int dx = 0; dx < ND; ++dx) {
    if (dx >= dlo && dx < dhi) {
      float4 o0 = make_float4((acc[dx][0] + red[dx][0][lane]) * scale,
                              (acc[dx][1] + red[dx][1][lane]) * scale,
                              (acc[dx][2] + red[dx][2][lane]) * scale,
                              (acc[dx][3] + red[dx][3][lane]) * scale);
      float4 o1 = make_float4((acc[dx][4] + red[dx][4][lane]) * scale,
                              (acc[dx][5] + red[dx][5][lane]) * scale,
                              (acc[dx][6] + red[dx][6][lane]) * scale,
                              (acc[dx][7] + red[dx][7][lane]) * scale);
      *(float4*)(obase + dx * HWn) = o0;
      *(float4*)(obase + dx * HWn + 4) = o1;
    }
  }
}

extern "C" void kernel_launch(void* const* d_in, const int* in_sizes, int n_in,
                              void* d_out, int out_size, void* d_ws, size_t ws_size,
                              hipStream_t stream) {
  const float* first = (const float*)d_in[0];
  const float* second = (const float*)d_in[1];
  float* out = (float*)d_out;
  corr_kernel<<<dim3(NBLK), dim3(NW * 64), 0, stream>>>(first, second, out);
}